// Round 1
// baseline (374.949 us; speedup 1.0000x reference)
//
#include <hip/hip_runtime.h>
#include <cstddef>

#define BB 16
#define CC 256
#define CI 128
#define KK3 384
#define NN 2048
#define BN_EPS 1e-5f

// workspace layout (float offsets)
#define OFF_W3   0u
#define OFF_B3   98304u                      // 384*256
#define OFF_TPG  98816u                      // padded
#define SZ_TPG   (16u*384u*2048u)            // 12582912
#define OFF_S    (OFF_TPG + SZ_TPG)          // 12681728
#define SZ_S     (16u*128u*128u)             // 262144
#define OFF_MP   (OFF_S + SZ_S)              // 12943872
#define SZ_MP    (16u*256u*128u)             // 524288
#define WS_FLOATS_NEEDED (OFF_MP + SZ_MP)    // 13468160 floats = ~53.9 MB

// ---------------------------------------------------------------------------
// K0: pack w_theta/w_phi/w_g into one [384,256] matrix + bias vector
// ---------------------------------------------------------------------------
__global__ __launch_bounds__(256) void pack_w(
    const float* __restrict__ wt, const float* __restrict__ bt,
    const float* __restrict__ wp, const float* __restrict__ bp,
    const float* __restrict__ wg, const float* __restrict__ bg,
    float* __restrict__ W3, float* __restrict__ bias3) {
  int gid = blockIdx.x * 256 + threadIdx.x;
  if (gid < KK3 * CC) {
    int k = gid >> 8;  // row (CC==256)
    float v;
    if (k < CI)          v = wt[gid];
    else if (k < 2 * CI) v = wp[gid - CI * CC];
    else                 v = wg[gid - 2 * CI * CC];
    W3[gid] = v;
  }
  if (gid < KK3) {
    float v = (gid < CI) ? bt[gid] : (gid < 2 * CI ? bp[gid - CI] : bg[gid - 2 * CI]);
    bias3[gid] = v;
  }
}

// ---------------------------------------------------------------------------
// K1: tpg[b,k,n] = sum_c W3[k,c]*x[b,c,n] + bias3[k]
// grid (NN/64, KK3/64, BB), block 256, 64x64 tile, K-step 16
// ---------------------------------------------------------------------------
__global__ __launch_bounds__(256) void gemm_tpg(
    const float* __restrict__ W3, const float* __restrict__ bias3,
    const float* __restrict__ x, float* __restrict__ tpg) {
  __shared__ __align__(16) float As[16][68];  // [kk][m], padded
  __shared__ __align__(16) float Bs[16][64];  // [kk][n]
  int n0 = blockIdx.x * 64;
  int m0 = blockIdx.y * 64;
  int b  = blockIdx.z;
  int t  = threadIdx.x;
  int tx = t & 15, ty = t >> 4;
  const float* xb = x + (size_t)b * CC * NN;
  float acc[4][4] = {};

  for (int kc = 0; kc < CC; kc += 16) {
    {  // stage A: W3 rows m0..m0+63, cols kc..kc+15
      int c = t & 15;
      int m = t >> 4;
#pragma unroll
      for (int r = 0; r < 4; ++r)
        As[c][m + 16 * r] = W3[(size_t)(m0 + m + 16 * r) * CC + kc + c];
    }
    {  // stage B: x rows kc..kc+15, cols n0..n0+63
      int n  = t & 63;
      int c4 = t >> 6;
#pragma unroll
      for (int r = 0; r < 4; ++r)
        Bs[c4 + 4 * r][n] = xb[(size_t)(kc + c4 + 4 * r) * NN + n0 + n];
    }
    __syncthreads();
#pragma unroll
    for (int kk = 0; kk < 16; ++kk) {
      float4 af = *reinterpret_cast<const float4*>(&As[kk][ty * 4]);
      float4 bf = *reinterpret_cast<const float4*>(&Bs[kk][tx * 4]);
      float a[4] = {af.x, af.y, af.z, af.w};
      float bv[4] = {bf.x, bf.y, bf.z, bf.w};
#pragma unroll
      for (int i = 0; i < 4; ++i)
#pragma unroll
        for (int j = 0; j < 4; ++j) acc[i][j] += a[i] * bv[j];
    }
    __syncthreads();
  }

  float* outb = tpg + (size_t)b * KK3 * NN;
#pragma unroll
  for (int i = 0; i < 4; ++i) {
    int m = m0 + ty * 4 + i;
    float bias = bias3[m];
    float4 ov;
    ov.x = acc[i][0] + bias; ov.y = acc[i][1] + bias;
    ov.z = acc[i][2] + bias; ov.w = acc[i][3] + bias;
    *reinterpret_cast<float4*>(&outb[(size_t)m * NN + n0 + tx * 4]) = ov;
  }
}

// ---------------------------------------------------------------------------
// K2: S[b,i,j] += sum_{n in chunk} g[b,i,n]*phi[b,j,n]   (split-K atomics)
// grid (16 chunks of 128 n, BB), block 256, 128x128 tile
// ---------------------------------------------------------------------------
__global__ __launch_bounds__(256) void gemm_S(
    const float* __restrict__ tpg, float* __restrict__ S) {
  __shared__ __align__(16) float Gs[16][132];
  __shared__ __align__(16) float Ps[16][132];
  int b = blockIdx.y;
  int nbase = blockIdx.x * 128;
  const float* gp = tpg + ((size_t)b * KK3 + 2 * CI) * NN;
  const float* pp = tpg + ((size_t)b * KK3 + CI) * NN;
  int t = threadIdx.x;
  int tx = t & 15, ty = t >> 4;
  float acc[8][8] = {};

  for (int nc = 0; nc < 128; nc += 16) {
    int nn = t & 15;
    int i0 = t >> 4;
#pragma unroll
    for (int r = 0; r < 8; ++r) {
      int i = i0 + 16 * r;
      size_t off = (size_t)i * NN + nbase + nc + nn;
      Gs[nn][i] = gp[off];
      Ps[nn][i] = pp[off];
    }
    __syncthreads();
#pragma unroll
    for (int k = 0; k < 16; ++k) {
      float4 a0 = *reinterpret_cast<const float4*>(&Gs[k][ty * 8]);
      float4 a1 = *reinterpret_cast<const float4*>(&Gs[k][ty * 8 + 4]);
      float4 b0 = *reinterpret_cast<const float4*>(&Ps[k][tx * 8]);
      float4 b1 = *reinterpret_cast<const float4*>(&Ps[k][tx * 8 + 4]);
      float a[8] = {a0.x, a0.y, a0.z, a0.w, a1.x, a1.y, a1.z, a1.w};
      float bv[8] = {b0.x, b0.y, b0.z, b0.w, b1.x, b1.y, b1.z, b1.w};
#pragma unroll
      for (int i = 0; i < 8; ++i)
#pragma unroll
        for (int j = 0; j < 8; ++j) acc[i][j] += a[i] * bv[j];
    }
    __syncthreads();
  }

  float* Sb = S + (size_t)b * CI * CI;
#pragma unroll
  for (int i = 0; i < 8; ++i)
#pragma unroll
    for (int j = 0; j < 8; ++j)
      atomicAdd(&Sb[(size_t)(ty * 8 + i) * CI + tx * 8 + j], acc[i][j]);
}

// ---------------------------------------------------------------------------
// K3: Mp[b,o,cj] = (inv[o]/N) * sum_ci w_out[o,ci] * S[b,ci,cj]
// grid (4 o-tiles of 64, BB), block 256; S[b] resident in LDS
// ---------------------------------------------------------------------------
__global__ __launch_bounds__(256) void gemm_M(
    const float* __restrict__ S, const float* __restrict__ w_out,
    const float* __restrict__ gamma, const float* __restrict__ run_var,
    float* __restrict__ Mp) {
  __shared__ __align__(16) float Sl[128][128];  // 64KB
  __shared__ __align__(16) float Wl[64][128];   // 32KB
  int b = blockIdx.y;
  int o0 = blockIdx.x * 64;
  int t = threadIdx.x;
  const float* Sb = S + (size_t)b * CI * CI;
#pragma unroll 4
  for (int r = 0; r < 64; ++r) {
    int idx = r * 256 + t;
    Sl[idx >> 7][idx & 127] = Sb[idx];
  }
#pragma unroll 4
  for (int r = 0; r < 32; ++r) {
    int idx = r * 256 + t;
    Wl[idx >> 7][idx & 127] = w_out[(size_t)o0 * CI + idx];
  }
  __syncthreads();

  int tx = t & 31, ty = t >> 5;  // tx: cj group (32x4), ty: o group (8x8)
  float acc[8][4] = {};
  for (int ci = 0; ci < 128; ++ci) {
    float4 sv = *reinterpret_cast<const float4*>(&Sl[ci][tx * 4]);
    float s[4] = {sv.x, sv.y, sv.z, sv.w};
#pragma unroll
    for (int i = 0; i < 8; ++i) {
      float w = Wl[ty * 8 + i][ci];
#pragma unroll
      for (int j = 0; j < 4; ++j) acc[i][j] += w * s[j];
    }
  }
#pragma unroll
  for (int i = 0; i < 8; ++i) {
    int o = o0 + ty * 8 + i;
    float inv = gamma[o] * rsqrtf(run_var[o] + BN_EPS);
    float sc = inv * (1.0f / (float)NN);
    float4 ov;
    ov.x = acc[i][0] * sc; ov.y = acc[i][1] * sc;
    ov.z = acc[i][2] * sc; ov.w = acc[i][3] * sc;
    *reinterpret_cast<float4*>(&Mp[((size_t)b * CC + o) * CI + tx * 4]) = ov;
  }
}

// ---------------------------------------------------------------------------
// K4: out[b,o,n] = sum_cj Mp[b,o,cj]*theta[b,cj,n] + bias'[o] + x[b,o,n]
// grid (NN/64, CC/64, BB), block 256, 64x64 tile, K=128
// ---------------------------------------------------------------------------
__global__ __launch_bounds__(256) void gemm_out(
    const float* __restrict__ Mp, const float* __restrict__ tpg,
    const float* __restrict__ x, const float* __restrict__ b_out,
    const float* __restrict__ gamma, const float* __restrict__ beta,
    const float* __restrict__ run_mean, const float* __restrict__ run_var,
    float* __restrict__ out) {
  __shared__ __align__(16) float As[16][68];
  __shared__ __align__(16) float Bs[16][64];
  int n0 = blockIdx.x * 64;
  int m0 = blockIdx.y * 64;
  int b  = blockIdx.z;
  int t  = threadIdx.x;
  int tx = t & 15, ty = t >> 4;
  const float* Ab = Mp + (size_t)b * CC * CI;
  const float* Tb = tpg + (size_t)b * KK3 * NN;  // theta = rows 0..127
  float acc[4][4] = {};

  for (int kc = 0; kc < CI; kc += 16) {
    {
      int c = t & 15;
      int m = t >> 4;
#pragma unroll
      for (int r = 0; r < 4; ++r)
        As[c][m + 16 * r] = Ab[(size_t)(m0 + m + 16 * r) * CI + kc + c];
    }
    {
      int n  = t & 63;
      int c4 = t >> 6;
#pragma unroll
      for (int r = 0; r < 4; ++r)
        Bs[c4 + 4 * r][n] = Tb[(size_t)(kc + c4 + 4 * r) * NN + n0 + n];
    }
    __syncthreads();
#pragma unroll
    for (int kk = 0; kk < 16; ++kk) {
      float4 af = *reinterpret_cast<const float4*>(&As[kk][ty * 4]);
      float4 bf = *reinterpret_cast<const float4*>(&Bs[kk][tx * 4]);
      float a[4] = {af.x, af.y, af.z, af.w};
      float bv[4] = {bf.x, bf.y, bf.z, bf.w};
#pragma unroll
      for (int i = 0; i < 4; ++i)
#pragma unroll
        for (int j = 0; j < 4; ++j) acc[i][j] += a[i] * bv[j];
    }
    __syncthreads();
  }

#pragma unroll
  for (int i = 0; i < 4; ++i) {
    int o = m0 + ty * 4 + i;
    float inv = gamma[o] * rsqrtf(run_var[o] + BN_EPS);
    float bias = b_out[o] * inv + beta[o] - run_mean[o] * inv;
    size_t idx = ((size_t)b * CC + o) * NN + n0 + tx * 4;
    float4 xv = *reinterpret_cast<const float4*>(&x[idx]);
    float4 ov;
    ov.x = acc[i][0] + bias + xv.x;
    ov.y = acc[i][1] + bias + xv.y;
    ov.z = acc[i][2] + bias + xv.z;
    ov.w = acc[i][3] + bias + xv.w;
    *reinterpret_cast<float4*>(&out[idx]) = ov;
  }
}

// ---------------------------------------------------------------------------
extern "C" void kernel_launch(void* const* d_in, const int* in_sizes, int n_in,
                              void* d_out, int out_size, void* d_ws, size_t ws_size,
                              hipStream_t stream) {
  const float* x        = (const float*)d_in[0];
  const float* w_theta  = (const float*)d_in[1];
  const float* b_theta  = (const float*)d_in[2];
  const float* w_phi    = (const float*)d_in[3];
  const float* b_phi    = (const float*)d_in[4];
  const float* w_g      = (const float*)d_in[5];
  const float* b_g      = (const float*)d_in[6];
  const float* w_out    = (const float*)d_in[7];
  const float* b_out    = (const float*)d_in[8];
  const float* gamma    = (const float*)d_in[9];
  const float* beta     = (const float*)d_in[10];
  const float* run_mean = (const float*)d_in[11];
  const float* run_var  = (const float*)d_in[12];
  float* out = (float*)d_out;
  float* ws  = (float*)d_ws;

  if (ws_size < (size_t)WS_FLOATS_NEEDED * sizeof(float)) return;  // insufficient scratch

  float* W3    = ws + OFF_W3;
  float* bias3 = ws + OFF_B3;
  float* tpg   = ws + OFF_TPG;
  float* S     = ws + OFF_S;
  float* Mp    = ws + OFF_MP;

  pack_w<<<dim3((KK3 * CC + 255) / 256), 256, 0, stream>>>(
      w_theta, b_theta, w_phi, b_phi, w_g, b_g, W3, bias3);
  hipMemsetAsync(S, 0, (size_t)SZ_S * sizeof(float), stream);
  gemm_tpg<<<dim3(NN / 64, KK3 / 64, BB), 256, 0, stream>>>(W3, bias3, x, tpg);
  gemm_S<<<dim3(16, BB), 256, 0, stream>>>(tpg, S);
  gemm_M<<<dim3(4, BB), 256, 0, stream>>>(S, w_out, gamma, run_var, Mp);
  gemm_out<<<dim3(NN / 64, CC / 64, BB), 256, 0, stream>>>(
      Mp, tpg, x, b_out, gamma, beta, run_mean, run_var, out);
}

// Round 9
// 172.963 us; speedup vs baseline: 2.1678x; 2.1678x over previous
//
#include <hip/hip_runtime.h>
#include <cstddef>
#include <cstdint>

typedef unsigned short ushort_t;
typedef short short8 __attribute__((ext_vector_type(8)));
typedef float f32x4 __attribute__((ext_vector_type(4)));

#define BB 16
#define CC 256
#define CI 128
#define KK3 384
#define NN 2048
#define BN_EPS 1e-5f
#define NCHUNK 8   // split-K chunks for S-gemm

// ---------------- workspace layout (float offsets, all 16B-aligned) -------
// NOTE: bf16 regions sized as (elem_count/2) floats. Round-4 bug: W3h was
// budgeted 24576 fl (elems/4); correct is 49152 fl -> everything shifted.
#define OFF_W3H   0u                          // 384*256 bf16   = 49152 fl
#define OFF_B3    49152u                      // 384 fl
#define OFF_B2    49536u                      // 256 fl (ends 49792)
#define OFF_XHT   49792u                      // 16*2048*256 bf16 = 4194304 fl
#define OFF_THT   4244096u                    // 16*2048*128 bf16 = 2097152 fl
#define OFF_TPG   6341248u                    // 16*256*2048 bf16 = 4194304 fl
#define OFF_SPART 10535552u                   // 8*16*16384 f32   = 2097152 fl
#define OFF_S     12632704u                   // 16*16384 f32     = 262144 fl
#define OFF_MH    12894848u                   // 16*256*128 bf16  = 262144 fl
#define WS_FLOATS 13156992u                   // ~52.6 MB

__device__ __forceinline__ ushort_t f2bf(float f) {
  unsigned int u = __float_as_uint(f);
  u += 0x7fffu + ((u >> 16) & 1u);
  return (ushort_t)(u >> 16);
}

__device__ __forceinline__ void gl_lds16(const void* gsrc, void* ldst) {
  __builtin_amdgcn_global_load_lds(
      (const __attribute__((address_space(1))) void*)gsrc,
      (__attribute__((address_space(3))) void*)ldst, 16, 0, 0);
}

// ---------------------------------------------------------------------------
// Shared MFMA core: C[128x128] tile, 4 waves (2x2), BK=64, bf16 16x16x32.
// A: rows of gA (M-dim), 16B-granule contiguous in K.  B: rows of gB (N-dim),
// contiguous in K (NT-gemm style).  ld* in ushort elements (multiple of 8).
// LDS linear dest via global_load_lds; source granule pre-swizzled ^(row&7);
// ds_read_b128 applies the same swizzle -> conflict-free fragment reads.
// ---------------------------------------------------------------------------
__device__ __forceinline__ void mfma_core(
    const ushort_t* gA, size_t ldA, const ushort_t* gB, size_t ldB,
    int kIters, ushort_t* ldsA, ushort_t* ldsB, f32x4 acc[4][4]) {
  const int t = threadIdx.x;
  const int wave = t >> 6, lane = t & 63;
  const int wm = wave & 1, wn = wave >> 1;
  const int l15 = lane & 15, lhi = lane >> 4;

  for (int kt = 0; kt < kIters; ++kt) {
#pragma unroll
    for (int q = 0; q < 4; ++q) {  // stage A: 128 rows x 64 ush (16KB)
      int row = wave * 32 + q * 8 + (lane >> 3);
      int gs = (lane & 7) ^ (row & 7);
      gl_lds16(gA + (size_t)row * ldA + gs * 8, &ldsA[(wave * 4 + q) * 512]);
    }
#pragma unroll
    for (int q = 0; q < 4; ++q) {  // stage B
      int row = wave * 32 + q * 8 + (lane >> 3);
      int gs = (lane & 7) ^ (row & 7);
      gl_lds16(gB + (size_t)row * ldB + gs * 8, &ldsB[(wave * 4 + q) * 512]);
    }
    __syncthreads();  // drains vmcnt -> LDS tiles ready
#pragma unroll
    for (int ks = 0; ks < 2; ++ks) {  // two k=32 steps per BK=64
      short8 af[4], bf[4];
#pragma unroll
      for (int i = 0; i < 4; ++i) {
        int rowA = wm * 64 + i * 16 + l15;
        int grA = (4 * ks + lhi) ^ (rowA & 7);
        af[i] = *(const short8*)&ldsA[rowA * 64 + grA * 8];
        int rowB = wn * 64 + i * 16 + l15;
        int grB = (4 * ks + lhi) ^ (rowB & 7);
        bf[i] = *(const short8*)&ldsB[rowB * 64 + grB * 8];
      }
#pragma unroll
      for (int i = 0; i < 4; ++i)
#pragma unroll
        for (int j = 0; j < 4; ++j)
          acc[i][j] = __builtin_amdgcn_mfma_f32_16x16x32_bf16(
              af[i], bf[j], acc[i][j], 0, 0, 0);
    }
    __syncthreads();
    gA += 64; gB += 64;
  }
}

// ---------------------------------------------------------------------------
// K0a: pack weights -> W3h bf16 [384][256], bias3 f32[384], bias2 f32[256]
// ---------------------------------------------------------------------------
__global__ __launch_bounds__(256) void pack_w(
    const float* __restrict__ wt, const float* __restrict__ bt,
    const float* __restrict__ wp, const float* __restrict__ bp,
    const float* __restrict__ wg, const float* __restrict__ bg,
    const float* __restrict__ b_out, const float* __restrict__ gamma,
    const float* __restrict__ beta, const float* __restrict__ run_mean,
    const float* __restrict__ run_var,
    ushort_t* __restrict__ W3h, float* __restrict__ bias3,
    float* __restrict__ bias2) {
  int gid = blockIdx.x * 256 + threadIdx.x;
  if (gid < KK3 * CC) {
    int k = gid >> 8;
    float v;
    if (k < CI)          v = wt[gid];
    else if (k < 2 * CI) v = wp[gid - CI * CC];
    else                 v = wg[gid - 2 * CI * CC];
    W3h[gid] = f2bf(v);
  }
  if (gid < KK3)
    bias3[gid] = (gid < CI) ? bt[gid] : (gid < 2 * CI ? bp[gid - CI] : bg[gid - 2 * CI]);
  if (gid < CC) {
    float inv = gamma[gid] * rsqrtf(run_var[gid] + BN_EPS);
    bias2[gid] = b_out[gid] * inv + beta[gid] - run_mean[gid] * inv;
  }
}

// ---------------------------------------------------------------------------
// K0b: transpose-cast x[b][c][n] f32 -> xhT[b][n][c] bf16 (LDS 64x64 tiles)
// ---------------------------------------------------------------------------
__global__ __launch_bounds__(256) void cast_xT(
    const float* __restrict__ x, ushort_t* __restrict__ xhT) {
  __shared__ float Xs[64][65];
  int n0 = blockIdx.x * 64, c0 = blockIdx.y * 64, b = blockIdx.z;
  int t = threadIdx.x;
  int tr = t >> 4, tc = (t & 15) * 4;
#pragma unroll
  for (int p = 0; p < 4; ++p) {
    int row = p * 16 + tr;  // c-local
    float4 v = *(const float4*)&x[((size_t)b * CC + c0 + row) * NN + n0 + tc];
    Xs[row][tc] = v.x; Xs[row][tc + 1] = v.y; Xs[row][tc + 2] = v.z; Xs[row][tc + 3] = v.w;
  }
  __syncthreads();
#pragma unroll
  for (int p = 0; p < 4; ++p) {
    int j = p * 16 + tr;  // n-local
    ushort4 hv;
    hv.x = f2bf(Xs[tc][j]); hv.y = f2bf(Xs[tc + 1][j]);
    hv.z = f2bf(Xs[tc + 2][j]); hv.w = f2bf(Xs[tc + 3][j]);
    *(ushort4*)&xhT[((size_t)b * NN + n0 + j) * CC + c0 + tc] = hv;
  }
}

// ---------------------------------------------------------------------------
// K1: D[n][m] = sum_c xhT[b][n][c]*W3[m][c] + bias3[m]
//     m-tile 0 (theta)  -> thT[b][n][m]   (coalesced, K4's B layout)
//     m-tiles 1,2 (phi,g) -> tpg_pg[b][m-128][n]  (K2's NT layout)
// grid (16 n-tiles, 3 m-tiles, 16 b)
// ---------------------------------------------------------------------------
__global__ __launch_bounds__(256) void k1_tpg(
    const ushort_t* __restrict__ xhT, const ushort_t* __restrict__ W3h,
    const float* __restrict__ bias3, ushort_t* __restrict__ thT,
    ushort_t* __restrict__ tpg_pg) {
  __shared__ __align__(16) ushort_t As[128 * 64], Bs[128 * 64];
  int n0 = blockIdx.x * 128, m0 = blockIdx.y * 128, b = blockIdx.z;
  f32x4 acc[4][4];
#pragma unroll
  for (int i = 0; i < 4; ++i)
#pragma unroll
    for (int j = 0; j < 4; ++j)
#pragma unroll
      for (int e = 0; e < 4; ++e) acc[i][j][e] = 0.f;

  mfma_core(xhT + ((size_t)b * NN + n0) * CC, CC,
            W3h + (size_t)m0 * CC, CC, CC / 64, As, Bs, acc);

  int t = threadIdx.x, wave = t >> 6, lane = t & 63;
  int wm = wave & 1, wn = wave >> 1, l15 = lane & 15, lhi = lane >> 4;
#pragma unroll
  for (int j = 0; j < 4; ++j) {
    int m = m0 + wn * 64 + j * 16 + l15;
    float bj = bias3[m];
#pragma unroll
    for (int i = 0; i < 4; ++i)
#pragma unroll
      for (int r = 0; r < 4; ++r) {
        int n = n0 + wm * 64 + i * 16 + 4 * lhi + r;
        ushort_t h = f2bf(acc[i][j][r] + bj);
        if (m0 == 0)
          thT[((size_t)b * NN + n) * CI + m] = h;
        else
          tpg_pg[((size_t)b * CC + (m - 128)) * NN + n] = h;
      }
  }
}

// ---------------------------------------------------------------------------
// K2: S_part[chunk][b][i][j] = sum_{n chunk} g[i][n]*phi[j][n]
// grid (NCHUNK, 16 b); A = g rows (tpg_pg rows 128..255), B = phi rows (0..127)
// ---------------------------------------------------------------------------
__global__ __launch_bounds__(256) void k2_S(
    const ushort_t* __restrict__ tpg_pg, float* __restrict__ S_part) {
  __shared__ __align__(16) ushort_t As[128 * 64], Bs[128 * 64];
  int chunk = blockIdx.x, b = blockIdx.y;
  int nbase = chunk * (NN / NCHUNK);
  f32x4 acc[4][4];
#pragma unroll
  for (int i = 0; i < 4; ++i)
#pragma unroll
    for (int j = 0; j < 4; ++j)
#pragma unroll
      for (int e = 0; e < 4; ++e) acc[i][j][e] = 0.f;

  mfma_core(tpg_pg + ((size_t)b * CC + CI) * NN + nbase, NN,
            tpg_pg + (size_t)b * CC * NN + nbase, NN,
            (NN / NCHUNK) / 64, As, Bs, acc);

  int t = threadIdx.x, wave = t >> 6, lane = t & 63;
  int wm = wave & 1, wn = wave >> 1, l15 = lane & 15, lhi = lane >> 4;
  float* dst = S_part + ((size_t)chunk * BB + b) * (CI * CI);
#pragma unroll
  for (int i = 0; i < 4; ++i)
#pragma unroll
    for (int j = 0; j < 4; ++j)
#pragma unroll
      for (int r = 0; r < 4; ++r) {
        int ig = wm * 64 + i * 16 + 4 * lhi + r;
        int jg = wn * 64 + j * 16 + l15;
        dst[(size_t)ig * CI + jg] = acc[i][j][r];
      }
}

// K2b: reduce slabs -> S[b][i][j] f32
__global__ __launch_bounds__(256) void k2b_reduce(
    const float* __restrict__ S_part, float* __restrict__ S) {
  int b = blockIdx.y;
  int e = blockIdx.x * 256 + threadIdx.x;  // 0..16383
  float s = 0.f;
#pragma unroll
  for (int c = 0; c < NCHUNK; ++c)
    s += S_part[((size_t)c * BB + b) * (CI * CI) + e];
  S[(size_t)b * (CI * CI) + e] = s;
}

// ---------------------------------------------------------------------------
// K3: Mh[b][o][cj] = bf16( (inv[o]/N) * sum_ci w_out[o][ci]*S[b][ci][cj] )
// grid (4 o-tiles of 64, 16 b); f32 math, S resident in LDS
// ---------------------------------------------------------------------------
__global__ __launch_bounds__(256) void gemm_M(
    const float* __restrict__ S, const float* __restrict__ w_out,
    const float* __restrict__ gamma, const float* __restrict__ run_var,
    ushort_t* __restrict__ Mh) {
  __shared__ __align__(16) float Sl[128][128];
  __shared__ __align__(16) float Wl[64][128];
  int b = blockIdx.y, o0 = blockIdx.x * 64, t = threadIdx.x;
  const float* Sb = S + (size_t)b * CI * CI;
#pragma unroll 4
  for (int r = 0; r < 64; ++r) {
    int idx = r * 256 + t;
    Sl[idx >> 7][idx & 127] = Sb[idx];
  }
#pragma unroll 4
  for (int r = 0; r < 32; ++r) {
    int idx = r * 256 + t;
    Wl[idx >> 7][idx & 127] = w_out[(size_t)o0 * CI + idx];
  }
  __syncthreads();

  int tx = t & 31, ty = t >> 5;
  float acc[8][4] = {};
  for (int ci = 0; ci < 128; ++ci) {
    float4 sv = *reinterpret_cast<const float4*>(&Sl[ci][tx * 4]);
    float s[4] = {sv.x, sv.y, sv.z, sv.w};
#pragma unroll
    for (int i = 0; i < 8; ++i) {
      float w = Wl[ty * 8 + i][ci];
#pragma unroll
      for (int j = 0; j < 4; ++j) acc[i][j] += w * s[j];
    }
  }
#pragma unroll
  for (int i = 0; i < 8; ++i) {
    int o = o0 + ty * 8 + i;
    float sc = gamma[o] * rsqrtf(run_var[o] + BN_EPS) * (1.0f / (float)NN);
    ushort4 hv;
    hv.x = f2bf(acc[i][0] * sc); hv.y = f2bf(acc[i][1] * sc);
    hv.z = f2bf(acc[i][2] * sc); hv.w = f2bf(acc[i][3] * sc);
    *(ushort4*)&Mh[((size_t)b * CC + o) * CI + tx * 4] = hv;
  }
}

// ---------------------------------------------------------------------------
// K4: out[b][o][n] = sum_cj Mh[b][o][cj]*thT[b][n][cj] + bias2[o] + x[b][o][n]
// grid (16 n-tiles, 2 o-tiles, 16 b)
// ---------------------------------------------------------------------------
__global__ __launch_bounds__(256) void k4_out(
    const ushort_t* __restrict__ Mh, const ushort_t* __restrict__ thT,
    const float* __restrict__ bias2, const float* __restrict__ x,
    float* __restrict__ out) {
  __shared__ __align__(16) ushort_t As[128 * 64], Bs[128 * 64];
  int n0 = blockIdx.x * 128, o0 = blockIdx.y * 128, b = blockIdx.z;
  f32x4 acc[4][4];
#pragma unroll
  for (int i = 0; i < 4; ++i)
#pragma unroll
    for (int j = 0; j < 4; ++j)
#pragma unroll
      for (int e = 0; e < 4; ++e) acc[i][j][e] = 0.f;

  mfma_core(Mh + ((size_t)b * CC + o0) * CI, CI,
            thT + ((size_t)b * NN + n0) * CI, CI, CI / 64, As, Bs, acc);

  int t = threadIdx.x, wave = t >> 6, lane = t & 63;
  int wm = wave & 1, wn = wave >> 1, l15 = lane & 15, lhi = lane >> 4;
#pragma unroll
  for (int i = 0; i < 4; ++i)
#pragma unroll
    for (int r = 0; r < 4; ++r) {
      int o = o0 + wm * 64 + i * 16 + 4 * lhi + r;
      float bo = bias2[o];
#pragma unroll
      for (int j = 0; j < 4; ++j) {
        int n = n0 + wn * 64 + j * 16 + l15;
        size_t idx = ((size_t)b * CC + o) * NN + n;
        out[idx] = acc[i][j][r] + bo + x[idx];
      }
    }
}

// ---------------------------------------------------------------------------
extern "C" void kernel_launch(void* const* d_in, const int* in_sizes, int n_in,
                              void* d_out, int out_size, void* d_ws, size_t ws_size,
                              hipStream_t stream) {
  const float* x        = (const float*)d_in[0];
  const float* w_theta  = (const float*)d_in[1];
  const float* b_theta  = (const float*)d_in[2];
  const float* w_phi    = (const float*)d_in[3];
  const float* b_phi    = (const float*)d_in[4];
  const float* w_g      = (const float*)d_in[5];
  const float* b_g      = (const float*)d_in[6];
  const float* w_out    = (const float*)d_in[7];
  const float* b_out    = (const float*)d_in[8];
  const float* gamma    = (const float*)d_in[9];
  const float* beta     = (const float*)d_in[10];
  const float* run_mean = (const float*)d_in[11];
  const float* run_var  = (const float*)d_in[12];
  float* out = (float*)d_out;
  float* ws  = (float*)d_ws;

  if (ws_size < (size_t)WS_FLOATS * sizeof(float)) return;

  ushort_t* W3h    = (ushort_t*)(ws + OFF_W3H);
  float*    bias3  = ws + OFF_B3;
  float*    bias2  = ws + OFF_B2;
  ushort_t* xhT    = (ushort_t*)(ws + OFF_XHT);
  ushort_t* thT    = (ushort_t*)(ws + OFF_THT);
  ushort_t* tpg_pg = (ushort_t*)(ws + OFF_TPG);
  float*    S_part = ws + OFF_SPART;
  float*    S      = ws + OFF_S;
  ushort_t* Mh     = (ushort_t*)(ws + OFF_MH);

  pack_w<<<dim3((KK3 * CC + 255) / 256), 256, 0, stream>>>(
      w_theta, b_theta, w_phi, b_phi, w_g, b_g,
      b_out, gamma, beta, run_mean, run_var, W3h, bias3, bias2);
  cast_xT<<<dim3(NN / 64, CC / 64, BB), 256, 0, stream>>>(x, xhT);
  k1_tpg<<<dim3(NN / 128, KK3 / 128, BB), 256, 0, stream>>>(
      xhT, W3h, bias3, thT, tpg_pg);
  k2_S<<<dim3(NCHUNK, BB), 256, 0, stream>>>(tpg_pg, S_part);
  k2b_reduce<<<dim3(CI * CI / 256, BB), 256, 0, stream>>>(S_part, S);
  gemm_M<<<dim3(4, BB), 256, 0, stream>>>(S, w_out, gamma, run_var, Mh);
  k4_out<<<dim3(NN / 128, CC / 128, BB), 256, 0, stream>>>(
      Mh, thT, bias2, x, out);
}